// Round 1
// baseline (398.147 us; speedup 1.0000x reference)
//
#include <hip/hip_runtime.h>

// Wav2Vec2BertSelfAttention on MI355X (gfx950)
// B=4, S=1024, HID=1024, NH=16, HD=64, LEFT=64, RIGHT=8, NUM_POS=73
//
// Pipeline:
//   1. cvt: f32->bf16 for X (hidden) and Wq/Wk/Wv/Wo
//   2. gemm_nt<colbias,bf16>: Q = X @ Wq^T + bq   -> [4096][1024] bf16
//   3. gemm_nt<colbias,bf16>: K = X @ Wk^T + bk   -> [4096][1024] bf16
//   4. gemm_nt<rowbias,bf16>: Vt = (Wv @ X^T) + bv -> [1024][4096] bf16  (= V transposed: [h*64+d][b*1024+s])
//   5. attn: per (b,h,16 q-rows): QK^T (MFMA) + qd-gather rel bias + softmax in regs,
//            write probs f32 to d_out, pack probs bf16 into swizzled LDS, PV (MFMA) -> ctx bf16
//   6. gemm_nt<colbias,f32>: out = ctx @ Wo^T + bo -> d_out[0 .. 4M)
//
// ws layout (needs 48 MB):
//   [0,8M)  Xbf  [8M,10M) Wq [10,12) Wk [12,14) Wv [14,16) Wo
//   [16,24) Q    [24,32) K   [32,40) Vt  [40,48) ctx

using short8 = __attribute__((ext_vector_type(8))) short;
using f32x4  = __attribute__((ext_vector_type(4))) float;
using fl4    = __attribute__((ext_vector_type(4))) float;
using u16x4  = __attribute__((ext_vector_type(4))) unsigned short;

#define MFMA16(a, b, c) __builtin_amdgcn_mfma_f32_16x16x32_bf16((a), (b), (c), 0, 0, 0)

__device__ __forceinline__ float bf2f(unsigned short u) {
  union { unsigned int i; float f; } c;
  c.i = ((unsigned int)u) << 16;
  return c.f;
}
__device__ __forceinline__ unsigned short f2bf(float f) {
  union { float f; unsigned int i; } c;
  c.f = f;
  unsigned int x = c.i;
  return (unsigned short)((x + 0x7fffu + ((x >> 16) & 1u)) >> 16);  // RNE
}

__device__ __forceinline__ void gload_lds16(const void* g, void* l) {
  __builtin_amdgcn_global_load_lds(
      (const __attribute__((address_space(1))) void*)g,
      (__attribute__((address_space(3))) void*)l, 16, 0, 0);
}

// ---------------------------------------------------------------- convert
__global__ void cvt_f32_bf16(const float* __restrict__ in,
                             unsigned short* __restrict__ out, int n4) {
  int i = blockIdx.x * blockDim.x + threadIdx.x;
  int stride = gridDim.x * blockDim.x;
  for (; i < n4; i += stride) {
    fl4 v = ((const fl4*)in)[i];
    u16x4 o;
    o[0] = f2bf(v[0]); o[1] = f2bf(v[1]); o[2] = f2bf(v[2]); o[3] = f2bf(v[3]);
    ((u16x4*)out)[i] = o;
  }
}

// ---------------------------------------------------------------- GEMM (NT)
// C[M][N] = A[M][K] @ B[N][K]^T + bias ; A,B bf16 row-major K-contiguous.
// 128x128 tile, BK=32, 256 threads (4 waves, 2x2), 4x4 16x16x32 frags/wave.
template <bool ROWBIAS, bool F32OUT>
__global__ __launch_bounds__(256)
void gemm_nt(const unsigned short* __restrict__ A,
             const unsigned short* __restrict__ B,
             const float* __restrict__ bias, void* __restrict__ Cp,
             int M, int N, int K) {
  __shared__ unsigned short lA[128 * 32];
  __shared__ unsigned short lB[128 * 32];
  const int tid = threadIdx.x;
  const int wave = tid >> 6, lane = tid & 63;
  const int wm = wave >> 1, wn = wave & 1;
  const int bm = blockIdx.x * 128, bn = blockIdx.y * 128;

  f32x4 acc[4][4];
#pragma unroll
  for (int m = 0; m < 4; ++m)
#pragma unroll
    for (int n = 0; n < 4; ++n) acc[m][n] = (f32x4){0.f, 0.f, 0.f, 0.f};

  // staging map: element t in [0,512): 16B chunk t covers row t/4, kcols (t%4)*8..+7
  const int t0 = tid, t1 = tid + 256;
  const int ar0 = t0 >> 2, ak0 = (t0 & 3) * 8;
  const int ar1 = t1 >> 2, ak1 = (t1 & 3) * 8;
  const size_t Ks = (size_t)K;
  const unsigned short* Ab = A + (size_t)bm * Ks;
  const unsigned short* Bb = B + (size_t)bn * Ks;

  const int fr = lane & 15, fk = (lane >> 4) * 8;

  for (int kt = 0; kt < K; kt += 32) {
    gload_lds16(Ab + (size_t)ar0 * Ks + kt + ak0, (void*)&lA[(wave * 64) * 8]);
    gload_lds16(Ab + (size_t)ar1 * Ks + kt + ak1, (void*)&lA[2048 + (wave * 64) * 8]);
    gload_lds16(Bb + (size_t)ar0 * Ks + kt + ak0, (void*)&lB[(wave * 64) * 8]);
    gload_lds16(Bb + (size_t)ar1 * Ks + kt + ak1, (void*)&lB[2048 + (wave * 64) * 8]);
    __syncthreads();
    short8 af[4], bf[4];
#pragma unroll
    for (int m = 0; m < 4; ++m)
      af[m] = *(const short8*)&lA[(wm * 64 + m * 16 + fr) * 32 + fk];
#pragma unroll
    for (int n = 0; n < 4; ++n)
      bf[n] = *(const short8*)&lB[(wn * 64 + n * 16 + fr) * 32 + fk];
#pragma unroll
    for (int m = 0; m < 4; ++m)
#pragma unroll
      for (int n = 0; n < 4; ++n) acc[m][n] = MFMA16(af[m], bf[n], acc[m][n]);
    __syncthreads();
  }

  // epilogue: C/D layout col=lane&15, row=(lane>>4)*4+reg  [m89-verified]
  const int cr = (lane >> 4) * 4, cc = lane & 15;
#pragma unroll
  for (int m = 0; m < 4; ++m) {
#pragma unroll
    for (int n = 0; n < 4; ++n) {
      const int col = bn + wn * 64 + n * 16 + cc;
#pragma unroll
      for (int g = 0; g < 4; ++g) {
        const int row = bm + wm * 64 + m * 16 + cr + g;
        float v = acc[m][n][g] + (ROWBIAS ? bias[row] : bias[col]);
        if (F32OUT)
          ((float*)Cp)[(size_t)row * N + col] = v;
        else
          ((unsigned short*)Cp)[(size_t)row * N + col] = f2bf(v);
      }
    }
  }
}

// ---------------------------------------------------------------- attention
// One block per (b, h, 16-row q-block). 256 threads = 4 waves.
// Wave w owns score cols [w*256, w*256+256). Scores live in 64 regs/lane.
__global__ __launch_bounds__(256)
void attn_kernel(const unsigned short* __restrict__ q,
                 const unsigned short* __restrict__ k,
                 const unsigned short* __restrict__ vt,
                 const float* __restrict__ demb,
                 float* __restrict__ probs,
                 unsigned short* __restrict__ ctx) {
  const int blk = blockIdx.x;
  const int lb = blk & 63;       // q-block within sequence (S/16 = 64)
  const int bh = blk >> 6;       // b*16 + h
  const int h = bh & 15, b = bh >> 4;
  const int tid = threadIdx.x, wave = tid >> 6, lane = tid & 63;

  __shared__ float sde[73 * 64];           // dist_emb copy
  __shared__ float qd[16][80];             // q . dist_emb[p], padded
  __shared__ unsigned short pb[16 * 1024]; // probs bf16, XOR-swizzled rows
  __shared__ float redm[4][16];
  __shared__ float reds[4][16];

  for (int i = tid; i < 73 * 64; i += 256) sde[i] = demb[i];

  const unsigned short* qb = q + (size_t)(b * 1024) * 1024 + h * 64;
  const unsigned short* qrow0 = qb + (size_t)(lb * 16) * 1024;

  __syncthreads();  // sde ready

  // qd[r][p] = q[row r] . dist_emb[p]
  for (int idx = tid; idx < 16 * 73; idx += 256) {
    const int r = idx / 73, p = idx - r * 73;
    const unsigned short* qr = qrow0 + (size_t)r * 1024;
    const float* e = &sde[p * 64];
    float s = 0.f;
#pragma unroll
    for (int d0 = 0; d0 < 64; d0 += 8) {
      short8 qv = *(const short8*)(qr + d0);
#pragma unroll
      for (int j = 0; j < 8; ++j) s += bf2f((unsigned short)qv[j]) * e[d0 + j];
    }
    qd[r][p] = s;
  }

  // Q fragments (A operand): row = lane&15, k = (lane>>4)*8 (+32 for ks=1)
  short8 afr[2];
  {
    const unsigned short* qa = qrow0 + (size_t)(lane & 15) * 1024 + ((lane >> 4) * 8);
    afr[0] = *(const short8*)qa;
    afr[1] = *(const short8*)(qa + 32);
  }

  // QK^T: 16 col-frags of 16, K=64 (2 mfma steps each)
  f32x4 sc[16];
#pragma unroll
  for (int f = 0; f < 16; ++f) sc[f] = (f32x4){0.f, 0.f, 0.f, 0.f};

  const int r0 = wave * 256;
  const unsigned short* kb = k + (size_t)(b * 1024) * 1024 + h * 64;
#pragma unroll
  for (int rt = 0; rt < 4; ++rt) {
#pragma unroll
    for (int n = 0; n < 4; ++n) {
      const unsigned short* kr =
          kb + (size_t)(r0 + rt * 64 + n * 16 + (lane & 15)) * 1024 + ((lane >> 4) * 8);
      short8 b0 = *(const short8*)kr;
      short8 b1 = *(const short8*)(kr + 32);
      sc[rt * 4 + n] = MFMA16(afr[0], b0, sc[rt * 4 + n]);
      sc[rt * 4 + n] = MFMA16(afr[1], b1, sc[rt * 4 + n]);
    }
  }

  __syncthreads();  // qd ready

  // scores = (qk + qd[l][clip(r-l)+64]) * 1/8 ; track per-row max
  const float scale = 0.125f;
  float rmax[4] = {-1e30f, -1e30f, -1e30f, -1e30f};
  const int rowb = (lane >> 4) * 4;
  const int lg0 = lb * 16;
#pragma unroll
  for (int f = 0; f < 16; ++f) {
    const int col = r0 + (f >> 2) * 64 + (f & 3) * 16 + (lane & 15);
#pragma unroll
    for (int g = 0; g < 4; ++g) {
      const int row = rowb + g;
      int d = col - (lg0 + row);
      d = (d < -64) ? -64 : (d > 8 ? 8 : d);
      float s = (sc[f][g] + qd[row][d + 64]) * scale;
      sc[f][g] = s;
      rmax[g] = fmaxf(rmax[g], s);
    }
  }
#pragma unroll
  for (int m = 1; m < 16; m <<= 1) {
#pragma unroll
    for (int g = 0; g < 4; ++g) rmax[g] = fmaxf(rmax[g], __shfl_xor(rmax[g], m, 64));
  }
  if ((lane & 15) == 0) {
#pragma unroll
    for (int g = 0; g < 4; ++g) redm[wave][rowb + g] = rmax[g];
  }
  __syncthreads();
  float gmax[4], rsum[4] = {0.f, 0.f, 0.f, 0.f};
#pragma unroll
  for (int g = 0; g < 4; ++g) {
    const int row = rowb + g;
    gmax[g] = fmaxf(fmaxf(redm[0][row], redm[1][row]), fmaxf(redm[2][row], redm[3][row]));
  }
#pragma unroll
  for (int f = 0; f < 16; ++f)
#pragma unroll
    for (int g = 0; g < 4; ++g) {
      float p = __expf(sc[f][g] - gmax[g]);
      sc[f][g] = p;
      rsum[g] += p;
    }
#pragma unroll
  for (int m = 1; m < 16; m <<= 1) {
#pragma unroll
    for (int g = 0; g < 4; ++g) rsum[g] += __shfl_xor(rsum[g], m, 64);
  }
  if ((lane & 15) == 0) {
#pragma unroll
    for (int g = 0; g < 4; ++g) reds[wave][rowb + g] = rsum[g];
  }
  __syncthreads();
  float ginv[4];
#pragma unroll
  for (int g = 0; g < 4; ++g) {
    const int row = rowb + g;
    ginv[g] = 1.0f / (reds[0][row] + reds[1][row] + reds[2][row] + reds[3][row]);
  }

  // write probs (f32, global) + pack bf16 into swizzled LDS for PV A-operand
  float* pout = probs + ((size_t)bh * 1024 + lg0) * 1024;
#pragma unroll
  for (int f = 0; f < 16; ++f) {
    const int col = r0 + (f >> 2) * 64 + (f & 3) * 16 + (lane & 15);
#pragma unroll
    for (int g = 0; g < 4; ++g) {
      const int row = rowb + g;
      float pv = sc[f][g] * ginv[g];
      pout[(size_t)row * 1024 + col] = pv;
      unsigned int off =
          ((unsigned)row * 2048u) + (((unsigned)col * 2u) ^ (((unsigned)row & 7u) << 4));
      *(unsigned short*)((char*)pb + off) = f2bf(pv);
    }
  }
  __syncthreads();

  // PV: wave w owns d-slice [w*16, w*16+16), full K=1024. ctx[l][d].
  f32x4 o = (f32x4){0.f, 0.f, 0.f, 0.f};
  const int arow = lane & 15, akg = (lane >> 4);
  const unsigned short* vb =
      vt + (size_t)(h * 64 + wave * 16 + (lane & 15)) * 4096 + (size_t)(b * 1024) + akg * 8;
#pragma unroll
  for (int ks = 0; ks < 32; ++ks) {
    unsigned int aoff = ((unsigned)arow * 2048u) +
                        (((unsigned)(ks * 64 + akg * 16)) ^ (((unsigned)arow & 7u) << 4));
    short8 a = *(const short8*)((char*)pb + aoff);
    short8 bv = *(const short8*)(vb + ks * 32);
    o = MFMA16(a, bv, o);
  }
  unsigned short* cb = ctx + (size_t)(b * 1024 + lg0) * 1024 + h * 64 + wave * 16;
#pragma unroll
  for (int g = 0; g < 4; ++g)
    cb[(size_t)(rowb + g) * 1024 + (lane & 15)] = f2bf(o[g]);
}

// ---------------------------------------------------------------- launch
extern "C" void kernel_launch(void* const* d_in, const int* in_sizes, int n_in,
                              void* d_out, int out_size, void* d_ws, size_t ws_size,
                              hipStream_t stream) {
  const float* hs = (const float*)d_in[0];
  const float* Wq = (const float*)d_in[1];
  const float* bq = (const float*)d_in[2];
  const float* Wk = (const float*)d_in[3];
  const float* bk = (const float*)d_in[4];
  const float* Wv = (const float*)d_in[5];
  const float* bv = (const float*)d_in[6];
  const float* Wo = (const float*)d_in[7];
  const float* bo = (const float*)d_in[8];
  const float* de = (const float*)d_in[9];

  float* out = (float*)d_out;
  float* probs = out + (size_t)4 * 1024 * 1024;

  char* ws = (char*)d_ws;
  unsigned short* Xb  = (unsigned short*)(ws);
  unsigned short* Wqb = (unsigned short*)(ws + ((size_t)8 << 20));
  unsigned short* Wkb = (unsigned short*)(ws + ((size_t)10 << 20));
  unsigned short* Wvb = (unsigned short*)(ws + ((size_t)12 << 20));
  unsigned short* Wob = (unsigned short*)(ws + ((size_t)14 << 20));
  unsigned short* Qb  = (unsigned short*)(ws + ((size_t)16 << 20));
  unsigned short* Kb  = (unsigned short*)(ws + ((size_t)24 << 20));
  unsigned short* Vt  = (unsigned short*)(ws + ((size_t)32 << 20));
  unsigned short* Cx  = (unsigned short*)(ws + ((size_t)40 << 20));

  cvt_f32_bf16<<<dim3(1024), dim3(256), 0, stream>>>(hs, Xb, (4 * 1024 * 1024) / 4);
  cvt_f32_bf16<<<dim3(256), dim3(256), 0, stream>>>(Wq, Wqb, (1024 * 1024) / 4);
  cvt_f32_bf16<<<dim3(256), dim3(256), 0, stream>>>(Wk, Wkb, (1024 * 1024) / 4);
  cvt_f32_bf16<<<dim3(256), dim3(256), 0, stream>>>(Wv, Wvb, (1024 * 1024) / 4);
  cvt_f32_bf16<<<dim3(256), dim3(256), 0, stream>>>(Wo, Wob, (1024 * 1024) / 4);

  // Q = X @ Wq^T + bq ; K = X @ Wk^T + bk   -> [4096][1024] bf16
  gemm_nt<false, false><<<dim3(32, 8), dim3(256), 0, stream>>>(Xb, Wqb, bq, Qb, 4096, 1024, 1024);
  gemm_nt<false, false><<<dim3(32, 8), dim3(256), 0, stream>>>(Xb, Wkb, bk, Kb, 4096, 1024, 1024);
  // Vt[o][n] = Wv[o] . X[n] + bv[o]  -> [1024][4096] bf16 (V transposed)
  gemm_nt<true, false><<<dim3(8, 32), dim3(256), 0, stream>>>(Wvb, Xb, bv, Vt, 1024, 4096, 1024);

  attn_kernel<<<dim3(4096), dim3(256), 0, stream>>>(Qb, Kb, Vt, de, probs, Cx);

  // out = ctx @ Wo^T + bo -> f32 d_out[0..4M)
  gemm_nt<false, true><<<dim3(32, 8), dim3(256), 0, stream>>>(Cx, Wob, bo, out, 4096, 1024, 1024);
}

// Round 2
// 289.712 us; speedup vs baseline: 1.3743x; 1.3743x over previous
//
#include <hip/hip_runtime.h>

// Wav2Vec2BertSelfAttention on MI355X (gfx950)
// B=4, S=1024, HID=1024, NH=16, HD=64, LEFT=64, RIGHT=8, NUM_POS=73
//
// Pipeline:
//   1. cvt: f32->bf16 for X (hidden) and Wq/Wk/Wv/Wo
//   2. gemm_nt: Q = X @ Wq^T + bq   -> [4096][1024] bf16
//   3. cvt_demb: dist_emb f32 -> bf16 [80][64] (padded), reusing Wq ws slot
//   4. gemm_nt: K = X @ Wk^T + bk; Vt = (Wv @ X^T)+bv -> [1024][4096] (V^T)
//   5. attn: per (b,h,16 q-rows): qd = Q@dist_emb^T via MFMA, QK^T via MFMA,
//            bias+softmax in regs, unnormalized-P bf16 in rotation-swizzled
//            LDS, coalesced f32 probs write, PV via MFMA (scale by 1/sum)
//   6. gemm_nt: out = ctx @ Wo^T + bo -> d_out[0..4M)
//
// ws layout (48 MB):
//   [0,8M) Xbf [8,10) Wq(->demb_bf after Q-gemm) [10,12) Wk [12,14) Wv
//   [14,16) Wo [16,24) Q [24,32) K [32,40) Vt [40,48) ctx

using short8 = __attribute__((ext_vector_type(8))) short;
using f32x4  = __attribute__((ext_vector_type(4))) float;
using fl4    = __attribute__((ext_vector_type(4))) float;
using u16x4  = __attribute__((ext_vector_type(4))) unsigned short;

#define MFMA16(a, b, c) __builtin_amdgcn_mfma_f32_16x16x32_bf16((a), (b), (c), 0, 0, 0)

__device__ __forceinline__ float bf2f(unsigned short u) {
  union { unsigned int i; float f; } c;
  c.i = ((unsigned int)u) << 16;
  return c.f;
}
__device__ __forceinline__ unsigned short f2bf(float f) {
  union { float f; unsigned int i; } c;
  c.f = f;
  unsigned int x = c.i;
  return (unsigned short)((x + 0x7fffu + ((x >> 16) & 1u)) >> 16);  // RNE
}

__device__ __forceinline__ void gload_lds16(const void* g, void* l) {
  __builtin_amdgcn_global_load_lds(
      (const __attribute__((address_space(1))) void*)g,
      (__attribute__((address_space(3))) void*)l, 16, 0, 0);
}

// ---------------------------------------------------------------- convert
__global__ void cvt_f32_bf16(const float* __restrict__ in,
                             unsigned short* __restrict__ out, int n4) {
  int i = blockIdx.x * blockDim.x + threadIdx.x;
  int stride = gridDim.x * blockDim.x;
  for (; i < n4; i += stride) {
    fl4 v = ((const fl4*)in)[i];
    u16x4 o;
    o[0] = f2bf(v[0]); o[1] = f2bf(v[1]); o[2] = f2bf(v[2]); o[3] = f2bf(v[3]);
    ((u16x4*)out)[i] = o;
  }
}

// dist_emb [73][64] f32 -> [80][64] bf16, rows 73..79 zeroed
__global__ void cvt_demb(const float* __restrict__ in,
                         unsigned short* __restrict__ out) {
  int i = blockIdx.x * blockDim.x + threadIdx.x;
  if (i < 80 * 64) out[i] = (i < 73 * 64) ? f2bf(in[i]) : (unsigned short)0;
}

// ---------------------------------------------------------------- GEMM (NT)
// C[M][N] = A[M][K] @ B[N][K]^T + bias ; A,B bf16 row-major K-contiguous.
// 128x128 tile, BK=32, 256 threads (4 waves, 2x2), 4x4 16x16x32 frags/wave.
template <bool ROWBIAS, bool F32OUT>
__global__ __launch_bounds__(256)
void gemm_nt(const unsigned short* __restrict__ A,
             const unsigned short* __restrict__ B,
             const float* __restrict__ bias, void* __restrict__ Cp,
             int M, int N, int K) {
  __shared__ unsigned short lA[128 * 32];
  __shared__ unsigned short lB[128 * 32];
  const int tid = threadIdx.x;
  const int wave = tid >> 6, lane = tid & 63;
  const int wm = wave >> 1, wn = wave & 1;
  const int bm = blockIdx.x * 128, bn = blockIdx.y * 128;

  f32x4 acc[4][4];
#pragma unroll
  for (int m = 0; m < 4; ++m)
#pragma unroll
    for (int n = 0; n < 4; ++n) acc[m][n] = (f32x4){0.f, 0.f, 0.f, 0.f};

  const int t0 = tid, t1 = tid + 256;
  const int ar0 = t0 >> 2, ak0 = (t0 & 3) * 8;
  const int ar1 = t1 >> 2, ak1 = (t1 & 3) * 8;
  const size_t Ks = (size_t)K;
  const unsigned short* Ab = A + (size_t)bm * Ks;
  const unsigned short* Bb = B + (size_t)bn * Ks;

  const int fr = lane & 15, fk = (lane >> 4) * 8;

  for (int kt = 0; kt < K; kt += 32) {
    gload_lds16(Ab + (size_t)ar0 * Ks + kt + ak0, (void*)&lA[(wave * 64) * 8]);
    gload_lds16(Ab + (size_t)ar1 * Ks + kt + ak1, (void*)&lA[2048 + (wave * 64) * 8]);
    gload_lds16(Bb + (size_t)ar0 * Ks + kt + ak0, (void*)&lB[(wave * 64) * 8]);
    gload_lds16(Bb + (size_t)ar1 * Ks + kt + ak1, (void*)&lB[2048 + (wave * 64) * 8]);
    __syncthreads();
    short8 af[4], bf[4];
#pragma unroll
    for (int m = 0; m < 4; ++m)
      af[m] = *(const short8*)&lA[(wm * 64 + m * 16 + fr) * 32 + fk];
#pragma unroll
    for (int n = 0; n < 4; ++n)
      bf[n] = *(const short8*)&lB[(wn * 64 + n * 16 + fr) * 32 + fk];
#pragma unroll
    for (int m = 0; m < 4; ++m)
#pragma unroll
      for (int n = 0; n < 4; ++n) acc[m][n] = MFMA16(af[m], bf[n], acc[m][n]);
    __syncthreads();
  }

  const int cr = (lane >> 4) * 4, cc = lane & 15;
#pragma unroll
  for (int m = 0; m < 4; ++m) {
#pragma unroll
    for (int n = 0; n < 4; ++n) {
      const int col = bn + wn * 64 + n * 16 + cc;
#pragma unroll
      for (int g = 0; g < 4; ++g) {
        const int row = bm + wm * 64 + m * 16 + cr + g;
        float v = acc[m][n][g] + (ROWBIAS ? bias[row] : bias[col]);
        if (F32OUT)
          ((float*)Cp)[(size_t)row * N + col] = v;
        else
          ((unsigned short*)Cp)[(size_t)row * N + col] = f2bf(v);
      }
    }
  }
}

// ---------------------------------------------------------------- attention
// One block per (b, h, 16-row q-block). 256 threads = 4 waves.
// Wave w owns score cols [w*256, w*256+256). Scores live in 64 regs/lane.
// pb holds UNNORMALIZED exp(s-max) in bf16, rotation-swizzled:
//   byte(row,col) = row*2048 + (((col + rot(row)*16) & 1023) * 2),
//   rot(row) = ((row&3) + (row>>2)) & 3   -- conflict-free for write (4
//   row-groups 32B apart), PV b128 read, and writeback b64 read.
__device__ __forceinline__ unsigned pbOff(int row, int col) {
  int rot = (((row & 3) + (row >> 2)) & 3) << 4;
  return ((unsigned)row << 11) + ((((unsigned)(col + rot)) & 1023u) << 1);
}

__global__ __launch_bounds__(256)
void attn_kernel(const unsigned short* __restrict__ q,
                 const unsigned short* __restrict__ k,
                 const unsigned short* __restrict__ vt,
                 const unsigned short* __restrict__ demb_bf,
                 float* __restrict__ probs,
                 unsigned short* __restrict__ ctx) {
  // XCD swizzle: all 64 q-blocks of one (b,h) land on one XCD's L2.
  const int i = blockIdx.x;
  const int xcd = i & 7, slot = i >> 3;
  const int bh = ((slot >> 6) << 3) + xcd;  // b*16 + h
  const int lb = slot & 63;                 // q-block within sequence
  const int h = bh & 15, b = bh >> 4;
  const int tid = threadIdx.x, wave = tid >> 6, lane = tid & 63;

  __shared__ unsigned short pb[16 * 1024];  // 32 KB
  __shared__ float qd[16][84];              // 5.25 KB
  __shared__ float redm[4][16];
  __shared__ float reds[4][16];

  const int lg0 = lb * 16;
  const unsigned short* qrow0 = q + ((size_t)(b * 1024 + lg0)) * 1024 + h * 64;

  // Q fragments (A operand): row = lane&15, k = (lane>>4)*8 (+32 for ks=1)
  short8 afr[2];
  {
    const unsigned short* qa = qrow0 + (size_t)(lane & 15) * 1024 + ((lane >> 4) * 8);
    afr[0] = *(const short8*)qa;
    afr[1] = *(const short8*)(qa + 32);
  }

  const int rowb = (lane >> 4) * 4;

  // qd[r][p] = q[r] . dist_emb[p] via MFMA (B = demb_bf rows p0..p0+15)
  for (int pg = wave; pg < 5; pg += 4) {
    const unsigned short* db =
        demb_bf + (size_t)(pg * 16 + (lane & 15)) * 64 + ((lane >> 4) * 8);
    short8 b0 = *(const short8*)db;
    short8 b1 = *(const short8*)(db + 32);
    f32x4 c = (f32x4){0.f, 0.f, 0.f, 0.f};
    c = MFMA16(afr[0], b0, c);
    c = MFMA16(afr[1], b1, c);
    const int p = pg * 16 + (lane & 15);
    if (p < 73) {
#pragma unroll
      for (int g = 0; g < 4; ++g) qd[rowb + g][p] = c[g];
    }
  }

  // QK^T: 16 col-frags of 16, K=64 (2 mfma steps each)
  f32x4 sc[16];
#pragma unroll
  for (int f = 0; f < 16; ++f) sc[f] = (f32x4){0.f, 0.f, 0.f, 0.f};

  const int r0 = wave * 256;
  const unsigned short* kb = k + (size_t)(b * 1024) * 1024 + h * 64;
#pragma unroll
  for (int rt = 0; rt < 4; ++rt) {
#pragma unroll
    for (int n = 0; n < 4; ++n) {
      const unsigned short* kr =
          kb + (size_t)(r0 + rt * 64 + n * 16 + (lane & 15)) * 1024 + ((lane >> 4) * 8);
      short8 b0 = *(const short8*)kr;
      short8 b1 = *(const short8*)(kr + 32);
      sc[rt * 4 + n] = MFMA16(afr[0], b0, sc[rt * 4 + n]);
      sc[rt * 4 + n] = MFMA16(afr[1], b1, sc[rt * 4 + n]);
    }
  }

  __syncthreads();  // qd ready

  // scores = (qk + qd[l][clip(r-l)+64]) * 1/8 ; per-row max
  const float scale = 0.125f;
  float rmax[4] = {-1e30f, -1e30f, -1e30f, -1e30f};
#pragma unroll
  for (int f = 0; f < 16; ++f) {
    const int col = r0 + (f >> 2) * 64 + (f & 3) * 16 + (lane & 15);
#pragma unroll
    for (int g = 0; g < 4; ++g) {
      const int row = rowb + g;
      int d = col - (lg0 + row);
      d = (d < -64) ? -64 : (d > 8 ? 8 : d);
      float s = (sc[f][g] + qd[row][d + 64]) * scale;
      sc[f][g] = s;
      rmax[g] = fmaxf(rmax[g], s);
    }
  }
#pragma unroll
  for (int m = 1; m < 16; m <<= 1)
#pragma unroll
    for (int g = 0; g < 4; ++g) rmax[g] = fmaxf(rmax[g], __shfl_xor(rmax[g], m, 64));
  if ((lane & 15) == 0) {
#pragma unroll
    for (int g = 0; g < 4; ++g) redm[wave][rowb + g] = rmax[g];
  }
  __syncthreads();
  float gmax[4], rsum[4] = {0.f, 0.f, 0.f, 0.f};
#pragma unroll
  for (int g = 0; g < 4; ++g) {
    const int row = rowb + g;
    gmax[g] = fmaxf(fmaxf(redm[0][row], redm[1][row]), fmaxf(redm[2][row], redm[3][row]));
  }

  // exp (unnormalized) -> pb bf16 + row sums
#pragma unroll
  for (int f = 0; f < 16; ++f) {
    const int col = r0 + (f >> 2) * 64 + (f & 3) * 16 + (lane & 15);
#pragma unroll
    for (int g = 0; g < 4; ++g) {
      float p = __expf(sc[f][g] - gmax[g]);
      rsum[g] += p;
      *(unsigned short*)((char*)pb + pbOff(rowb + g, col)) = f2bf(p);
    }
  }
#pragma unroll
  for (int m = 1; m < 16; m <<= 1)
#pragma unroll
    for (int g = 0; g < 4; ++g) rsum[g] += __shfl_xor(rsum[g], m, 64);
  if ((lane & 15) == 0) {
#pragma unroll
    for (int g = 0; g < 4; ++g) reds[wave][rowb + g] = rsum[g];
  }
  __syncthreads();  // pb + reds ready

  // coalesced probs write: thread t -> row t>>4, cols (t&15)*4 + c*64
  {
    const int wrow = tid >> 4, wl = tid & 15;
    const float inv =
        1.0f / (reds[0][wrow] + reds[1][wrow] + reds[2][wrow] + reds[3][wrow]);
    float* prow = probs + ((size_t)bh * 1024 + lg0 + wrow) * 1024;
#pragma unroll
    for (int c = 0; c < 16; ++c) {
      const int col = wl * 4 + c * 64;
      u16x4 v = *(const u16x4*)((const char*)pb + pbOff(wrow, col));
      f32x4 o4;
      o4[0] = bf2f(v[0]) * inv;
      o4[1] = bf2f(v[1]) * inv;
      o4[2] = bf2f(v[2]) * inv;
      o4[3] = bf2f(v[3]) * inv;
      *(f32x4*)&prow[col] = o4;
    }
  }

  // PV: wave w owns d-slice [w*16, +16), K=1024, unnormalized P; scale at end
  float ginv[4];
#pragma unroll
  for (int g = 0; g < 4; ++g) {
    const int row = rowb + g;
    ginv[g] = 1.0f / (reds[0][row] + reds[1][row] + reds[2][row] + reds[3][row]);
  }
  f32x4 o = (f32x4){0.f, 0.f, 0.f, 0.f};
  const int arow = lane & 15, akg = (lane >> 4);
  const unsigned short* vb =
      vt + (size_t)(h * 64 + wave * 16 + arow) * 4096 + (size_t)(b * 1024) + akg * 8;
#pragma unroll
  for (int ks = 0; ks < 32; ++ks) {
    short8 a = *(const short8*)((char*)pb + pbOff(arow, ks * 32 + akg * 8));
    short8 bv = *(const short8*)(vb + ks * 32);
    o = MFMA16(a, bv, o);
  }
  unsigned short* cb = ctx + (size_t)(b * 1024 + lg0) * 1024 + h * 64 + wave * 16;
#pragma unroll
  for (int g = 0; g < 4; ++g)
    cb[(size_t)(rowb + g) * 1024 + arow] = f2bf(o[g] * ginv[g]);
}

// ---------------------------------------------------------------- launch
extern "C" void kernel_launch(void* const* d_in, const int* in_sizes, int n_in,
                              void* d_out, int out_size, void* d_ws, size_t ws_size,
                              hipStream_t stream) {
  const float* hs = (const float*)d_in[0];
  const float* Wq = (const float*)d_in[1];
  const float* bq = (const float*)d_in[2];
  const float* Wk = (const float*)d_in[3];
  const float* bk = (const float*)d_in[4];
  const float* Wv = (const float*)d_in[5];
  const float* bv = (const float*)d_in[6];
  const float* Wo = (const float*)d_in[7];
  const float* bo = (const float*)d_in[8];
  const float* de = (const float*)d_in[9];

  float* out = (float*)d_out;
  float* probs = out + (size_t)4 * 1024 * 1024;

  char* ws = (char*)d_ws;
  unsigned short* Xb  = (unsigned short*)(ws);
  unsigned short* Wqb = (unsigned short*)(ws + ((size_t)8 << 20));
  unsigned short* Wkb = (unsigned short*)(ws + ((size_t)10 << 20));
  unsigned short* Wvb = (unsigned short*)(ws + ((size_t)12 << 20));
  unsigned short* Wob = (unsigned short*)(ws + ((size_t)14 << 20));
  unsigned short* Qb  = (unsigned short*)(ws + ((size_t)16 << 20));
  unsigned short* Kb  = (unsigned short*)(ws + ((size_t)24 << 20));
  unsigned short* Vt  = (unsigned short*)(ws + ((size_t)32 << 20));
  unsigned short* Cx  = (unsigned short*)(ws + ((size_t)40 << 20));
  unsigned short* Db  = Wqb;  // demb_bf reuses Wq slot after the Q-gemm

  cvt_f32_bf16<<<dim3(1024), dim3(256), 0, stream>>>(hs, Xb, (4 * 1024 * 1024) / 4);
  cvt_f32_bf16<<<dim3(256), dim3(256), 0, stream>>>(Wq, Wqb, (1024 * 1024) / 4);
  cvt_f32_bf16<<<dim3(256), dim3(256), 0, stream>>>(Wk, Wkb, (1024 * 1024) / 4);
  cvt_f32_bf16<<<dim3(256), dim3(256), 0, stream>>>(Wv, Wvb, (1024 * 1024) / 4);
  cvt_f32_bf16<<<dim3(256), dim3(256), 0, stream>>>(Wo, Wob, (1024 * 1024) / 4);

  gemm_nt<false, false><<<dim3(32, 8), dim3(256), 0, stream>>>(Xb, Wqb, bq, Qb, 4096, 1024, 1024);
  cvt_demb<<<dim3(20), dim3(256), 0, stream>>>(de, Db);  // after Q-gemm (slot reuse)
  gemm_nt<false, false><<<dim3(32, 8), dim3(256), 0, stream>>>(Xb, Wkb, bk, Kb, 4096, 1024, 1024);
  gemm_nt<true, false><<<dim3(8, 32), dim3(256), 0, stream>>>(Wvb, Xb, bv, Vt, 1024, 4096, 1024);

  attn_kernel<<<dim3(4096), dim3(256), 0, stream>>>(Qb, Kb, Vt, Db, probs, Cx);

  gemm_nt<false, true><<<dim3(32, 8), dim3(256), 0, stream>>>(Cx, Wob, bo, out, 4096, 1024, 1024);
}